// Round 9
// baseline (69.473 us; speedup 1.0000x reference)
//
#include <hip/hip_runtime.h>
#include <hip/hip_fp16.h>

#define NC 16384        // num classes == batch
#define FD 128          // feature dim
#define LAMBDA 0.005f
#define SLOTCAP 64      // max samples tracked per class (Poisson(1): max ~10)
#define CHUNK 64        // K rows per gram block
#define NCH (NC / CHUNK)  // 256 K-chunks per matrix

__device__ __forceinline__ float wave_sum(float v) {
#pragma unroll
  for (int m = 32; m > 0; m >>= 1) v += __shfl_xor(v, m, 64);
  return v;
}

// --- 0. zero cnt + scal/ticket ------------------------------------------------
__global__ __launch_bounds__(256) void zero_kernel(int4* __restrict__ cnt4,
                                                   float* __restrict__ scal) {
  cnt4[blockIdx.x * 256 + threadIdx.x] = make_int4(0, 0, 0, 0);
  if (blockIdx.x == 0 && threadIdx.x < 16) scal[threadIdx.x] = 0.f;
}

// --- 1. scatter: slot[lab][k] = sample index -----------------------------------
__global__ __launch_bounds__(256) void scatter_kernel(
    const int* __restrict__ labels, int* __restrict__ cnt, int* __restrict__ slot) {
  int i = blockIdx.x * 256 + threadIdx.x;
  int lab = labels[i];
  int p = atomicAdd(&cnt[lab], 1);
  if (p < SLOTCAP) slot[(size_t)lab * SLOTCAP + p] = i;
}

// --- 2. centers + diag: one wave per class -------------------------------------
__global__ __launch_bounds__(256) void center_kernel(
    const float* __restrict__ z, const int* __restrict__ cnt,
    const int* __restrict__ slot, float* __restrict__ cn,
    float2* __restrict__ dpart) {
  __shared__ float red[8];
  int t = threadIdx.x, wave = t >> 6, lane = t & 63;
  int c = blockIdx.x * 4 + wave;

  int n = cnt[c];
  if (n > SLOTCAP) n = SLOTCAP;
  float2 s = make_float2(0.f, 0.f);
  for (int k = 0; k < n; ++k) {
    int i = slot[(size_t)c * SLOTCAP + k];
    float2 v = *(const float2*)&z[(size_t)i * FD + lane * 2];
    s.x += v.x; s.y += v.y;
  }
  float inv = n > 0 ? 1.0f / (float)n : 0.0f;
  s.x *= inv; s.y *= inv;
  float sc = wave_sum(s.x * s.x + s.y * s.y);
  float ic = 1.0f / fmaxf(sqrtf(sc), 1e-12f);
  s.x *= ic; s.y *= ic;
  *(float2*)&cn[(size_t)c * FD + lane * 2] = s;

  // diag: d_c = (z_c / ||z_c||) . cn_c
  float2 a = *(const float2*)&z[(size_t)c * FD + lane * 2];
  float na = wave_sum(a.x * a.x + a.y * a.y);
  float dd = wave_sum(a.x * s.x + a.y * s.y);
  float d = dd * (1.0f / fmaxf(sqrtf(na), 1e-12f));
  if (lane == 0) { red[wave * 2] = d; red[wave * 2 + 1] = d * d; }
  __syncthreads();
  if (t == 0) {
    dpart[blockIdx.x] = make_float2(red[0] + red[2] + red[4] + red[6],
                                    red[1] + red[3] + red[5] + red[7]);
  }
}

// --- 3. gram partials: 1024 blocks = {matrix m, col-half h, chunk} -------------
// Output: 128 rows (all d) x 64 cols (h*64..), fp16 partial. 4 blocks/CU.
__global__ __launch_bounds__(256) void gram_kernel(
    const float* __restrict__ z, const float* __restrict__ cn,
    __half2* __restrict__ pz, __half2* __restrict__ pc) {
  __shared__ float tile[CHUNK * FD];  // 32 KB
  int t = threadIdx.x, wave = t >> 6, lane = t & 63;
  int b = blockIdx.x;
  int m = b & 1;               // matrix: 0=z, 1=centers
  int h = (b >> 1) & 1;        // column half
  int chunk = b >> 2;          // [0, NCH)
  const float* A = m ? cn : z;
  const float4* t4 = (const float4*)tile;

  {  // stage 64x128 floats, coalesced float4
    const float4* src = (const float4*)&A[(size_t)chunk * CHUNK * FD];
    float4* dst = (float4*)tile;
#pragma unroll
    for (int k = 0; k < 8; ++k) dst[k * 256 + t] = src[k * 256 + t];
  }
  __syncthreads();
  if (m == 0) {  // normalize z rows in LDS (16 rows per wave)
    float2* t2 = (float2*)tile;
#pragma unroll
    for (int j = 0; j < 16; ++j) {
      int row = wave * 16 + j;
      float2 v = t2[row * 64 + lane];
      float ss = wave_sum(v.x * v.x + v.y * v.y);
      float sc = 1.0f / fmaxf(sqrtf(ss), 1e-12f);
      v.x *= sc; v.y *= sc;
      t2[row * 64 + lane] = v;
    }
    __syncthreads();
  }

  // per-thread patch: rows d0=ty*4..+3, cols e0=h*64+tx*8..+7
  int tx = t & 7, ty = t >> 3;  // tx 0..7, ty 0..31
  float4 acc[4][2];
#pragma unroll
  for (int i = 0; i < 4; ++i) {
    acc[i][0] = make_float4(0.f, 0.f, 0.f, 0.f);
    acc[i][1] = make_float4(0.f, 0.f, 0.f, 0.f);
  }
  float4 a4 = t4[ty];
  float4 b0 = t4[h * 16 + tx * 2];
  float4 b1 = t4[h * 16 + tx * 2 + 1];
  for (int r = 0; r < CHUNK; ++r) {
    int rn = (r + 1) & (CHUNK - 1);
    float4 na = t4[rn * 32 + ty];
    float4 nb0 = t4[rn * 32 + h * 16 + tx * 2];
    float4 nb1 = t4[rn * 32 + h * 16 + tx * 2 + 1];
    float av[4] = {a4.x, a4.y, a4.z, a4.w};
#pragma unroll
    for (int i = 0; i < 4; ++i) {
      float a = av[i];
      acc[i][0].x += a * b0.x;
      acc[i][0].y += a * b0.y;
      acc[i][0].z += a * b0.z;
      acc[i][0].w += a * b0.w;
      acc[i][1].x += a * b1.x;
      acc[i][1].y += a * b1.y;
      acc[i][1].z += a * b1.z;
      acc[i][1].w += a * b1.w;
    }
    a4 = na; b0 = nb0; b1 = nb1;
  }

  // fp16 partial store: [chunk][h] layout, 128x64 halves = 4096 half2 per block
  __half2* P = (m ? pc : pz) + ((size_t)chunk * 2 + h) * 4096;
#pragma unroll
  for (int i = 0; i < 4; ++i) {
    int d = ty * 4 + i;
    __half2 h0 = __floats2half2_rn(acc[i][0].x, acc[i][0].y);
    __half2 h1 = __floats2half2_rn(acc[i][0].z, acc[i][0].w);
    __half2 h2 = __floats2half2_rn(acc[i][1].x, acc[i][1].y);
    __half2 h3 = __floats2half2_rn(acc[i][1].z, acc[i][1].w);
    uint4 u = make_uint4(*(unsigned*)&h0, *(unsigned*)&h1,
                         *(unsigned*)&h2, *(unsigned*)&h3);
    *(uint4*)&P[d * 32 + tx * 4] = u;
  }
}

// --- 4. reduce fp16 partials + Frobenius + final loss (last-block ticket) ------
__global__ __launch_bounds__(256) void reduce_final_kernel(
    const __half2* __restrict__ pz, const __half2* __restrict__ pc,
    const float2* __restrict__ dpart, float* __restrict__ scal,
    float* __restrict__ out) {
  __shared__ float2 lz[4][64], lc[4][64];
  int t = threadIdx.x, wave = t >> 6, lane = t & 63;
  int e2 = blockIdx.x * 64 + lane;  // half2 index in [0, 8192)
  float2 sz = make_float2(0.f, 0.f), sc = make_float2(0.f, 0.f);
  for (int k = 0; k < NCH / 4; ++k) {
    size_t c = (size_t)(wave * (NCH / 4) + k) * 8192 + e2;
    float2 fz = __half22float2(pz[c]);
    float2 fc = __half22float2(pc[c]);
    sz.x += fz.x; sz.y += fz.y;
    sc.x += fc.x; sc.y += fc.y;
  }
  lz[wave][lane] = sz;
  lc[wave][lane] = sc;
  __syncthreads();
  if (wave == 0) {
    float2 tz = make_float2(0.f, 0.f), tc = make_float2(0.f, 0.f);
#pragma unroll
    for (int w = 0; w < 4; ++w) {
      tz.x += lz[w][lane].x; tz.y += lz[w][lane].y;
      tc.x += lc[w][lane].x; tc.y += lc[w][lane].y;
    }
    float S = wave_sum(tz.x * tc.x + tz.y * tc.y);
    int* ticket_p = (int*)&scal[8];
    int ticket = 0;
    if (lane == 0) {
      unsafeAtomicAdd(&scal[2], S);
      __threadfence();
      ticket = atomicAdd(ticket_p, 1);
    }
    ticket = __shfl(ticket, 0, 64);
    if (ticket == 127) {  // last block: compose the loss
      float a1 = 0.f, a2 = 0.f;
      for (int k = lane; k < 4096; k += 64) {
        float2 d = dpart[k];
        a1 += d.x; a2 += d.y;
      }
      a1 = wave_sum(a1);
      a2 = wave_sum(a2);
      if (lane == 0) {
        float SS = atomicAdd(&scal[2], 0.0f);  // coherent read of total
        double S1 = a1, S2 = a2, Sall = SS;
        double B = (double)NC;
        double inv_loss = S2 / (B * B) - 2.0 * S1 / B + (double)NC;
        double red_loss = (Sall - S2) / (B * B);
        out[0] = (float)(inv_loss + (double)LAMBDA * red_loss);
      }
    }
  }
}

extern "C" void kernel_launch(void* const* d_in, const int* in_sizes, int n_in,
                              void* d_out, int out_size, void* d_ws, size_t ws_size,
                              hipStream_t stream) {
  const float* z = (const float*)d_in[0];
  const int* labels = (const int*)d_in[1];
  float* out = (float*)d_out;
  float* ws = (float*)d_ws;

  // ws layout (floats):
  // [cn NC*FD][pz NCH*2*4096 half2][pc same][dpart 2*4096][scal 16][cnt NC][slot NC*SLOTCAP]
  float* cn = ws;
  __half2* pz = (__half2*)(cn + (size_t)NC * FD);
  __half2* pc = pz + (size_t)NCH * 2 * 4096;
  float2* dpart = (float2*)(pc + (size_t)NCH * 2 * 4096);
  float* scal = (float*)(dpart + 4096);
  int* cnt = (int*)(scal + 16);
  int* slot = cnt + NC;

  zero_kernel<<<NC / 1024, 256, 0, stream>>>((int4*)cnt, scal);
  scatter_kernel<<<NC / 256, 256, 0, stream>>>(labels, cnt, slot);
  center_kernel<<<NC / 4, 256, 0, stream>>>(z, cnt, slot, cn, dpart);
  gram_kernel<<<4 * NCH, 256, 0, stream>>>(z, cn, pz, pc);
  reduce_final_kernel<<<128, 256, 0, stream>>>(pz, pc, dpart, scal, out);
}